// Round 7
// baseline (217.963 us; speedup 1.0000x reference)
//
#include <hip/hip_runtime.h>
#include <hip/hip_bf16.h>
#include <math.h>

// (B,Cin,H,W)=(8,128,64,64), Cout=256, K=3, stride=1, pad=1, dil=1
#define B_    8
#define CIN   128
#define Hx    64
#define Wx    64
#define COUT  256
#define HW    4096
#define KTOT  1152      // CIN*9
#define NOFF  18
#define M_    32768     // B*HW
#define OFFSEG (B_ * NOFF * HW)   // 589824 floats per cin-segment partial
#define NCH   36        // K-chunks (chunk = 32 k)

typedef short bf16x8 __attribute__((ext_vector_type(8)));
typedef float f32x4  __attribute__((ext_vector_type(4)));

typedef __attribute__((address_space(1))) const unsigned int gu32;
typedef __attribute__((address_space(3))) unsigned int lu32;
static __device__ __forceinline__ void async_cp16(const short* g, short* l) {
  __builtin_amdgcn_global_load_lds((gu32*)g, (lu32*)l, 16, 0, 0);
}

static __device__ __forceinline__ short f2bf(float f) {
  __hip_bfloat16 h = __float2bfloat16(f);
  return *reinterpret_cast<short*>(&h);
}

static __device__ __forceinline__ float b2f(unsigned short u) {
  unsigned int v = ((unsigned int)u) << 16;
  return __uint_as_float(v);
}

// ---------------- K1: offset conv (round-8 proven) ----------------
__global__ __launch_bounds__(256, 4) void offset_conv_kernel(
    const float* __restrict__ x, const float* __restrict__ ow,
    const float* __restrict__ ob, float* __restrict__ offp) {
  __shared__ __align__(16) float lds_w[16 * 9 * 12];   // [ci][ch][12 (9 taps + pad)]
  int blk = blockIdx.x;                     // 0..1023
  int r = blk & 63, seg = (blk >> 6) & 7, chalf = blk >> 9;
  int tid = threadIdx.x;
  for (int i = tid; i < 16 * 9 * 12; i += 256) {
    int t = i % 12;
    int rem = i / 12;                       // ci*9 + ch
    int ch = rem % 9, ci = rem / 9;
    lds_w[i] = (t < 9) ? ow[(chalf * 9 + ch) * KTOT + (seg * 16 + ci) * 9 + t] : 0.f;
  }
  __syncthreads();

  int v = r * 256 + tid;                    // 0..16383
  int wp = v & 31, ho = (v >> 5) & 63, b = v >> 11;
  int wo0 = wp * 2;
  float acc0[9], acc1[9];
#pragma unroll
  for (int c = 0; c < 9; ++c) { acc0[c] = 0.f; acc1[c] = 0.f; }
  const float* xb = x + (b * CIN + seg * 16) * HW;
  for (int ci = 0; ci < 16; ++ci) {
    const float* xp = xb + ci * HW;
    float win[3][4];
#pragma unroll
    for (int ky = 0; ky < 3; ++ky) {
      int iy = ho - 1 + ky;
      bool rok = (iy >= 0) & (iy < Hx);
      const float* rowp = xp + iy * Wx;
#pragma unroll
      for (int c = 0; c < 4; ++c) {
        int ix = wo0 - 1 + c;
        win[ky][c] = (rok & (ix >= 0) & (ix < Wx)) ? rowp[ix] : 0.f;
      }
    }
    const float4* wq = (const float4*)&lds_w[ci * 108];
#pragma unroll
    for (int ch = 0; ch < 9; ++ch) {
      float4 w0 = wq[ch * 3 + 0];
      float4 w1 = wq[ch * 3 + 1];
      float4 w2 = wq[ch * 3 + 2];
      float a0 = acc0[ch], a1 = acc1[ch];
      a0 = fmaf(win[0][0], w0.x, a0); a1 = fmaf(win[0][1], w0.x, a1);
      a0 = fmaf(win[0][1], w0.y, a0); a1 = fmaf(win[0][2], w0.y, a1);
      a0 = fmaf(win[0][2], w0.z, a0); a1 = fmaf(win[0][3], w0.z, a1);
      a0 = fmaf(win[1][0], w0.w, a0); a1 = fmaf(win[1][1], w0.w, a1);
      a0 = fmaf(win[1][1], w1.x, a0); a1 = fmaf(win[1][2], w1.x, a1);
      a0 = fmaf(win[1][2], w1.y, a0); a1 = fmaf(win[1][3], w1.y, a1);
      a0 = fmaf(win[2][0], w1.z, a0); a1 = fmaf(win[2][1], w1.z, a1);
      a0 = fmaf(win[2][1], w1.w, a0); a1 = fmaf(win[2][2], w1.w, a1);
      a0 = fmaf(win[2][2], w2.x, a0); a1 = fmaf(win[2][3], w2.x, a1);
      acc0[ch] = a0; acc1[ch] = a1;
    }
  }
  float* op = offp + seg * OFFSEG + (b * NOFF + chalf * 9) * HW + ho * 64 + wo0;
#pragma unroll
  for (int c = 0; c < 9; ++c) {
    float bias = (seg == 0) ? ob[chalf * 9 + c] : 0.f;
    op[c * HW]     = acc0[c] + bias;
    op[c * HW + 1] = acc1[c] + bias;
  }
}

// ---------------- K2: weight -> bf16 blocked Wb[kc][cout][32] (proven) ----------------
__global__ __launch_bounds__(256) void wt_cvt_kernel(
    const float* __restrict__ w, short* __restrict__ Wb) {
  int t = blockIdx.x * 256 + threadIdx.x;   // 294912
  int ki = t & 31;
  int cout = (t >> 5) & 255;
  int kc = t >> 13;                         // 0..35
  int k = kc * 32 + ki;
  int kk = k >> 7, cin = k & 127;
  Wb[t] = f2bf(w[(cout * CIN + cin) * 9 + kk]);
}

// ---------------- K3: bilinear coefficient tables (proven, 8 partials) ----------------
__global__ __launch_bounds__(256) void coeff_kernel(
    const float* __restrict__ offp, short4* __restrict__ cidx, float4* __restrict__ cwt) {
  int t = blockIdx.x * 256 + threadIdx.x;   // 9*32768
  int m = t & (M_ - 1);
  int kk = t >> 15;                         // 0..8
  int b = m >> 12, ho = (m >> 6) & 63, wo = m & 63;
  int base = (b * NOFF + 2 * kk) * HW + (m & 4095);
  int base2 = base + HW;
  float dy = 0.f, dx = 0.f;
#pragma unroll
  for (int s = 0; s < 8; ++s) {
    dy += offp[base + s * OFFSEG];
    dx += offp[base2 + s * OFFSEG];
  }
  float sy = (float)(ho - 1 + kk / 3) + dy;
  float sx = (float)(wo - 1 + kk % 3) + dx;
  float fy = floorf(sy), fx = floorf(sx);
  int y0 = (int)fy, x0 = (int)fx;
  float wy = sy - fy, wx = sx - fx;
  int y1 = y0 + 1, x1 = x0 + 1;
  int cy0 = min(max(y0, 0), Hx - 1), cy1 = min(max(y1, 0), Hx - 1);
  int cx0 = min(max(x0, 0), Wx - 1), cx1 = min(max(x1, 0), Wx - 1);
  bool vy0 = (y0 >= 0) & (y0 < Hx), vy1 = (y1 >= 0) & (y1 < Hx);
  bool vx0 = (x0 >= 0) & (x0 < Wx), vx1 = (x1 >= 0) & (x1 < Wx);
  short4 id;
  id.x = (short)(cy0 * Wx + cx0); id.y = (short)(cy0 * Wx + cx1);
  id.z = (short)(cy1 * Wx + cx0); id.w = (short)(cy1 * Wx + cx1);
  float4 wv;
  wv.x = (vy0 && vx0) ? (1.f - wy) * (1.f - wx) : 0.f;
  wv.y = (vy0 && vx1) ? (1.f - wy) * wx : 0.f;
  wv.z = (vy1 && vx0) ? wy * (1.f - wx) : 0.f;
  wv.w = (vy1 && vx1) ? wy * wx : 0.f;
  cidx[t] = id;
  cwt[t] = wv;
}

// ---------------- K4: sampler v7 — v6 + double-buffered coeff prefetch ----------------
// Post-mortem v6 (53us, CONFIRMED theory): 4-cin amortization halved time;
// every pipe still <=20% busy (VALU 15 = exactly the instr count, LDS ~18%,
// VMEM tiny) -> pure latency exposure: each iteration's serial chain
// (coeff L2 load -> LDS gather -> FMA -> store) is paid nearly in full with
// only ~2.4 waves/SIMD to interleave. v5 showed same-batch load batching is
// useless; v7 decouples ISSUE from USE across batches (T14 pattern):
//   flat pipeline over 8-iter batches (crossing kk boundaries):
//     issue batch t+1's 16 coeff loads into the ALTERNATE register set
//     sched_barrier(0)
//     gather+compute+store batch t  (~1100cy VALU+LDS covers the load latency)
// Named A/B buffers, all indices compile-time (no scratch). Only the
// prologue pays one exposed coeff wait per block.
// blk = (kq<<8)|(g4<<3)|b, grid 1024, 32KB LDS. Pb layout unchanged.
#define SAMPLE_BATCH(IDV, WVV)                                               \
  _Pragma("unroll")                                                          \
  for (int u = 0; u < 8; ++u) {                                              \
    short4 id = IDV[u]; float4 wv = WVV[u];                                  \
    ushort4 A  = ldsp[(int)id.x];                                            \
    ushort4 Bv = ldsp[(int)id.y];                                            \
    ushort4 C  = ldsp[(int)id.z];                                            \
    ushort4 D  = ldsp[(int)id.w];                                            \
    float s0 = wv.x * b2f(A.x) + wv.y * b2f(Bv.x) + wv.z * b2f(C.x) + wv.w * b2f(D.x); \
    float s1 = wv.x * b2f(A.y) + wv.y * b2f(Bv.y) + wv.z * b2f(C.y) + wv.w * b2f(D.y); \
    float s2 = wv.x * b2f(A.z) + wv.y * b2f(Bv.z) + wv.z * b2f(C.z) + wv.w * b2f(D.z); \
    float s3 = wv.x * b2f(A.w) + wv.y * b2f(Bv.w) + wv.z * b2f(C.w) + wv.w * b2f(D.w); \
    union { short s[4]; int2 v; } bu;                                        \
    bu.s[0] = f2bf(s0); bu.s[1] = f2bf(s1);                                  \
    bu.s[2] = f2bf(s2); bu.s[3] = f2bf(s3);                                  \
    *(int2*)&pb[u * 256 * 32] = bu.v;                                        \
  }

__global__ __launch_bounds__(256) void sampler_kernel(
    const float* __restrict__ x, const short4* __restrict__ cidx,
    const float4* __restrict__ cwt, short* __restrict__ Pb) {
  __shared__ __align__(16) ushort4 ldsp[HW];   // 32768 B: [pixel]{4 bf16 cins}
  int blk = blockIdx.x;                     // 0..1023
  int b = blk & 7;
  int g4 = (blk >> 3) & 31;                 // cin-quad 0..31
  int kq = blk >> 8;                        // 0..3
  int cinq = g4 >> 3;                       // chunk quarter 0..3
  int e = g4 & 7;                           // quad slot within chunk (8 quads)
  int tid = threadIdx.x;

  // stage 4 planes -> bf16 interleaved. Coalesced f32 reads, 8B LDS writes.
  const float* p0 = x + (b * CIN + g4 * 4) * HW;
  const float* p1 = p0 + HW;
  const float* p2 = p0 + 2 * HW;
  const float* p3 = p0 + 3 * HW;
#pragma unroll
  for (int it = 0; it < 16; ++it) {
    int p = it * 256 + tid;
    ushort4 pk;
    pk.x = (unsigned short)f2bf(p0[p]);
    pk.y = (unsigned short)f2bf(p1[p]);
    pk.z = (unsigned short)f2bf(p2[p]);
    pk.w = (unsigned short)f2bf(p3[p]);
    ldsp[p] = pk;
  }
  __syncthreads();

  int kk0 = (kq == 0) ? 0 : (kq * 2 + 1);   // {0,3,5,7}
  int nkk = (kq == 0) ? 3 : 2;
  int nb = nkk * 2;                         // 8-iter batches, flat across kk
  const int cb = b * HW + tid;

  short4 idA[8]; float4 wvA[8];
  short4 idB[8]; float4 wvB[8];

  // prologue: batch 0 -> A (the only exposed coeff wait per block)
  {
    const short4* cp0 = cidx + kk0 * M_ + cb;
    const float4* wp0 = cwt + kk0 * M_ + cb;
#pragma unroll
    for (int u = 0; u < 8; ++u) { idA[u] = cp0[u * 256]; wvA[u] = wp0[u * 256]; }
  }

  for (int t = 0; t < nb; ++t) {
    int kk = kk0 + (t >> 1);
    // ---- issue prefetch of batch t+1 into the non-current buffer ----
    if (t + 1 < nb) {
      int kkn = kk0 + ((t + 1) >> 1);
      int offn = ((t + 1) & 1) * 2048;
      const short4* cpn = cidx + kkn * M_ + cb + offn;
      const float4* wpn = cwt + kkn * M_ + cb + offn;
      if ((t & 1) == 0) {
#pragma unroll
        for (int u = 0; u < 8; ++u) { idB[u] = cpn[u * 256]; wvB[u] = wpn[u * 256]; }
      } else {
#pragma unroll
        for (int u = 0; u < 8; ++u) { idA[u] = cpn[u * 256]; wvA[u] = wpn[u * 256]; }
      }
    }
    __builtin_amdgcn_sched_barrier(0);      // prefetch issues BEFORE compute
    // ---- compute current batch ----
    int kcg = kk * 4 + cinq;                // 0..35
    short* pb = Pb + (kcg * M_ + b * HW + (t & 1) * 2048 + tid) * 32 + e * 4;
    if ((t & 1) == 0) {
      SAMPLE_BATCH(idA, wvA)
    } else {
      SAMPLE_BATCH(idB, wvB)
    }
  }
}

// ---------------- K5: single bf16 MFMA GEMM, m97-style async K-loop ----------------
// blk: mt = blk&255, ct = blk>>8 (ct-pair shares XCD -> Pb L2 reuse).
// Tile 128 cout x 128 m, K=1152 in 36 chunks of 32. Double-buffered 16KB LDS
// tiles staged by global_load_lds (flat 8KB A + 8KB B copies); ONE barrier per
// chunk; next chunk's DMA flies across the 16 MFMAs.
__global__ __launch_bounds__(256, 2) void gemm_kernel(
    const short* __restrict__ Wb, const short* __restrict__ Pb,
    float* __restrict__ y) {
  __shared__ __align__(16) short lds[2][8192];   // [buf][ A 4096 | B 4096 ] shorts

  int tid = threadIdx.x;
  int mt = blockIdx.x & 255;
  int ct = blockIdx.x >> 8;
  int cout0 = ct * 128;
  int m0 = mt * 128;

  int lane = tid & 63, wave = tid >> 6;
  int quad = lane >> 4, l16 = lane & 15;
  int wm = (wave & 1) << 6;          // cout sub-tile 0/64
  int wnm = (wave >> 1) << 6;        // m sub-tile 0/64

  // staging roles: waves 0,1 -> A halves; waves 2,3 -> B halves
  int isB = wave >> 1;
  int sub = wave & 1;
  const short* srcbase = isB ? (Pb + m0 * 32) : (Wb + cout0 * 32);
  const int sstride = isB ? (M_ * 32) : (256 * 32);
  const int soff = sub * 2048 + lane * 8;        // shorts
  const int doff = isB * 4096 + sub * 2048 + lane * 8;

  f32x4 zero = {0.f, 0.f, 0.f, 0.f};
  f32x4 acc[4][4];
#pragma unroll
  for (int i = 0; i < 4; ++i)
#pragma unroll
    for (int j = 0; j < 4; ++j) acc[i][j] = zero;

  // prologue: chunk 0 -> buf 0
  {
    const short* s = srcbase + soff;
    short* d = &lds[0][doff];
#pragma unroll
    for (int j = 0; j < 4; ++j)
      async_cp16(s + j * 512, d + j * 512);
  }

  for (int ch = 0; ch < NCH; ++ch) {
    int p = ch & 1;
    __syncthreads();                 // drains DMA -> buf p ready; frag reads of p^1 done
    if (ch < NCH - 1) {
      const short* s = srcbase + (ch + 1) * sstride + soff;
      short* d = &lds[p ^ 1][doff];
#pragma unroll
      for (int j = 0; j < 4; ++j)
        async_cp16(s + j * 512, d + j * 512);   // flies across the MFMAs below
    }
    const short* sa = &lds[p][0];
    const short* sb = &lds[p][4096];
    bf16x8 af[4], bfr[4];
#pragma unroll
    for (int i = 0; i < 4; ++i)
      af[i] = *(const bf16x8*)&sa[(wm + i * 16 + l16) * 32 + quad * 8];
#pragma unroll
    for (int j = 0; j < 4; ++j)
      bfr[j] = *(const bf16x8*)&sb[(wnm + j * 16 + l16) * 32 + quad * 8];
#pragma unroll
    for (int i = 0; i < 4; ++i)
#pragma unroll
      for (int j = 0; j < 4; ++j)
        acc[i][j] = __builtin_amdgcn_mfma_f32_16x16x32_bf16(af[i], bfr[j], acc[i][j], 0, 0, 0);
  }

  // epilogue: write y once (dconv bias cancels in BN mean-subtraction)
#pragma unroll
  for (int i = 0; i < 4; ++i) {
    int crow = cout0 + wm + i * 16 + quad * 4;
#pragma unroll
    for (int j = 0; j < 4; ++j) {
      int m = m0 + wnm + j * 16 + l16;
      int b = m >> 12;
      float* yp = y + (b * COUT + crow) * HW + (m & 4095);
#pragma unroll
      for (int r2 = 0; r2 < 4; ++r2)
        yp[r2 * HW] = acc[i][j][r2];
    }
  }
}

// ---------------- K6: BN batch stats (proven) ----------------
__global__ __launch_bounds__(256) void bn_stats_kernel(
    const float* __restrict__ y, float* __restrict__ mean, float* __restrict__ invstd) {
  int c = blockIdx.x;
  int tid = threadIdx.x;
  float s = 0.f, s2 = 0.f;
  for (int b = 0; b < B_; ++b) {
    const float4* p = (const float4*)(y + (b * COUT + c) * HW);
    for (int i = tid; i < HW / 4; i += 256) {
      float4 v = p[i];
      s += v.x + v.y + v.z + v.w;
      s2 = fmaf(v.x, v.x, s2); s2 = fmaf(v.y, v.y, s2);
      s2 = fmaf(v.z, v.z, s2); s2 = fmaf(v.w, v.w, s2);
    }
  }
#pragma unroll
  for (int o = 32; o > 0; o >>= 1) {
    s  += __shfl_down(s, o);
    s2 += __shfl_down(s2, o);
  }
  __shared__ float rs[4], rs2[4];
  int wid = tid >> 6, ln = tid & 63;
  if (ln == 0) { rs[wid] = s; rs2[wid] = s2; }
  __syncthreads();
  if (tid == 0) {
    float S  = rs[0] + rs[1] + rs[2] + rs[3];
    float S2 = rs2[0] + rs2[1] + rs2[2] + rs2[3];
    float m = S / 32768.f;
    float var = S2 / 32768.f - m * m;
    mean[c] = m;
    invstd[c] = rsqrtf(var + 1e-5f);
  }
}

// ---------------- K7: BN apply + SiLU, in place on y (= d_out) (proven) ----------------
__global__ __launch_bounds__(256) void bn_silu_kernel(
    float* __restrict__ y, const float* __restrict__ mean,
    const float* __restrict__ invstd, const float* __restrict__ gamma,
    const float* __restrict__ beta) {
  int i4 = blockIdx.x * 256 + threadIdx.x;   // 2097152 float4s
  int c = (i4 >> 10) & 255;
  float4 v = ((const float4*)y)[i4];
  float m = mean[c], sc = invstd[c] * gamma[c], bt = beta[c];
  float t0 = (v.x - m) * sc + bt;
  float t1 = (v.y - m) * sc + bt;
  float t2 = (v.z - m) * sc + bt;
  float t3 = (v.w - m) * sc + bt;
  float4 o;
  o.x = t0 / (1.f + expf(-t0));
  o.y = t1 / (1.f + expf(-t1));
  o.z = t2 / (1.f + expf(-t2));
  o.w = t3 / (1.f + expf(-t3));
  ((float4*)y)[i4] = o;
}

extern "C" void kernel_launch(void* const* d_in, const int* in_sizes, int n_in,
                              void* d_out, int out_size, void* d_ws, size_t ws_size,
                              hipStream_t stream) {
  const float* x     = (const float*)d_in[0];
  const float* ow    = (const float*)d_in[1];
  const float* ob    = (const float*)d_in[2];
  const float* dw    = (const float*)d_in[3];
  // d_in[4] = dconv bias: cancelled exactly by BN mean-subtraction
  const float* gamma = (const float*)d_in[5];
  const float* beta  = (const float*)d_in[6];
  float* y = (float*)d_out;                  // 8*256*4096 f32 — y buffer, finished in place

  // ws layout (float offsets), total 25,510,400 floats = 102.0 MB (ws = 256 MiB)
  float*  ws   = (float*)d_ws;
  short*  Pb   = (short*)ws;                 // 36*32768*32 shorts = 18874368 floats
  float*  offp = ws + 18874368;              // 8 * 589824 = 4718592
  short4* cidx = (short4*)(ws + 23592960);   // 9*32768 short4 = 589824 floats
  float4* cwt  = (float4*)(ws + 24182784);   // 9*32768 float4 = 1179648 floats
  short*  Wb   = (short*)(ws + 25362432);    // 294912 shorts = 147456 floats
  float*  mean   = ws + 25509888;            // 256
  float*  invstd = ws + 25510144;            // 256

  offset_conv_kernel<<<1024, 256, 0, stream>>>(x, ow, ob, offp);
  wt_cvt_kernel<<<1152, 256, 0, stream>>>(dw, Wb);
  coeff_kernel<<<1152, 256, 0, stream>>>(offp, cidx, cwt);
  sampler_kernel<<<1024, 256, 0, stream>>>(x, cidx, cwt, Pb);
  gemm_kernel<<<512, 256, 0, stream>>>(Wb, Pb, y);
  bn_stats_kernel<<<256, 256, 0, stream>>>(y, mean, invstd);
  bn_silu_kernel<<<8192, 256, 0, stream>>>(y, mean, invstd, gamma, beta);
}

// Round 8
// 213.528 us; speedup vs baseline: 1.0208x; 1.0208x over previous
//
#include <hip/hip_runtime.h>
#include <hip/hip_bf16.h>
#include <math.h>

// (B,Cin,H,W)=(8,128,64,64), Cout=256, K=3, stride=1, pad=1, dil=1
#define B_    8
#define CIN   128
#define Hx    64
#define Wx    64
#define COUT  256
#define HW    4096
#define KTOT  1152      // CIN*9
#define NOFF  18
#define M_    32768     // B*HW
#define OFFSEG (B_ * NOFF * HW)   // 589824 floats per cin-segment partial
#define NCH   36        // K-chunks (chunk = 32 k)

typedef short bf16x8 __attribute__((ext_vector_type(8)));
typedef float f32x4  __attribute__((ext_vector_type(4)));

typedef __attribute__((address_space(1))) const unsigned int gu32;
typedef __attribute__((address_space(3))) unsigned int lu32;
static __device__ __forceinline__ void async_cp16(const short* g, short* l) {
  __builtin_amdgcn_global_load_lds((gu32*)g, (lu32*)l, 16, 0, 0);
}

static __device__ __forceinline__ short f2bf(float f) {
  __hip_bfloat16 h = __float2bfloat16(f);
  return *reinterpret_cast<short*>(&h);
}

static __device__ __forceinline__ float b2f(unsigned short u) {
  unsigned int v = ((unsigned int)u) << 16;
  return __uint_as_float(v);
}

// ---------------- K1: offset conv (round-8 proven) ----------------
__global__ __launch_bounds__(256, 4) void offset_conv_kernel(
    const float* __restrict__ x, const float* __restrict__ ow,
    const float* __restrict__ ob, float* __restrict__ offp) {
  __shared__ __align__(16) float lds_w[16 * 9 * 12];   // [ci][ch][12 (9 taps + pad)]
  int blk = blockIdx.x;                     // 0..1023
  int r = blk & 63, seg = (blk >> 6) & 7, chalf = blk >> 9;
  int tid = threadIdx.x;
  for (int i = tid; i < 16 * 9 * 12; i += 256) {
    int t = i % 12;
    int rem = i / 12;                       // ci*9 + ch
    int ch = rem % 9, ci = rem / 9;
    lds_w[i] = (t < 9) ? ow[(chalf * 9 + ch) * KTOT + (seg * 16 + ci) * 9 + t] : 0.f;
  }
  __syncthreads();

  int v = r * 256 + tid;                    // 0..16383
  int wp = v & 31, ho = (v >> 5) & 63, b = v >> 11;
  int wo0 = wp * 2;
  float acc0[9], acc1[9];
#pragma unroll
  for (int c = 0; c < 9; ++c) { acc0[c] = 0.f; acc1[c] = 0.f; }
  const float* xb = x + (b * CIN + seg * 16) * HW;
  for (int ci = 0; ci < 16; ++ci) {
    const float* xp = xb + ci * HW;
    float win[3][4];
#pragma unroll
    for (int ky = 0; ky < 3; ++ky) {
      int iy = ho - 1 + ky;
      bool rok = (iy >= 0) & (iy < Hx);
      const float* rowp = xp + iy * Wx;
#pragma unroll
      for (int c = 0; c < 4; ++c) {
        int ix = wo0 - 1 + c;
        win[ky][c] = (rok & (ix >= 0) & (ix < Wx)) ? rowp[ix] : 0.f;
      }
    }
    const float4* wq = (const float4*)&lds_w[ci * 108];
#pragma unroll
    for (int ch = 0; ch < 9; ++ch) {
      float4 w0 = wq[ch * 3 + 0];
      float4 w1 = wq[ch * 3 + 1];
      float4 w2 = wq[ch * 3 + 2];
      float a0 = acc0[ch], a1 = acc1[ch];
      a0 = fmaf(win[0][0], w0.x, a0); a1 = fmaf(win[0][1], w0.x, a1);
      a0 = fmaf(win[0][1], w0.y, a0); a1 = fmaf(win[0][2], w0.y, a1);
      a0 = fmaf(win[0][2], w0.z, a0); a1 = fmaf(win[0][3], w0.z, a1);
      a0 = fmaf(win[1][0], w0.w, a0); a1 = fmaf(win[1][1], w0.w, a1);
      a0 = fmaf(win[1][1], w1.x, a0); a1 = fmaf(win[1][2], w1.x, a1);
      a0 = fmaf(win[1][2], w1.y, a0); a1 = fmaf(win[1][3], w1.y, a1);
      a0 = fmaf(win[2][0], w1.z, a0); a1 = fmaf(win[2][1], w1.z, a1);
      a0 = fmaf(win[2][1], w1.w, a0); a1 = fmaf(win[2][2], w1.w, a1);
      a0 = fmaf(win[2][2], w2.x, a0); a1 = fmaf(win[2][3], w2.x, a1);
      acc0[ch] = a0; acc1[ch] = a1;
    }
  }
  float* op = offp + seg * OFFSEG + (b * NOFF + chalf * 9) * HW + ho * 64 + wo0;
#pragma unroll
  for (int c = 0; c < 9; ++c) {
    float bias = (seg == 0) ? ob[chalf * 9 + c] : 0.f;
    op[c * HW]     = acc0[c] + bias;
    op[c * HW + 1] = acc1[c] + bias;
  }
}

// ---------------- K2: weight -> bf16 blocked Wb[kc][cout][32] (proven) ----------------
__global__ __launch_bounds__(256) void wt_cvt_kernel(
    const float* __restrict__ w, short* __restrict__ Wb) {
  int t = blockIdx.x * 256 + threadIdx.x;   // 294912
  int ki = t & 31;
  int cout = (t >> 5) & 255;
  int kc = t >> 13;                         // 0..35
  int k = kc * 32 + ki;
  int kk = k >> 7, cin = k & 127;
  Wb[t] = f2bf(w[(cout * CIN + cin) * 9 + kk]);
}

// ---------------- K3: bilinear coefficient tables (proven, 8 partials) ----------------
__global__ __launch_bounds__(256) void coeff_kernel(
    const float* __restrict__ offp, short4* __restrict__ cidx, float4* __restrict__ cwt) {
  int t = blockIdx.x * 256 + threadIdx.x;   // 9*32768
  int m = t & (M_ - 1);
  int kk = t >> 15;                         // 0..8
  int b = m >> 12, ho = (m >> 6) & 63, wo = m & 63;
  int base = (b * NOFF + 2 * kk) * HW + (m & 4095);
  int base2 = base + HW;
  float dy = 0.f, dx = 0.f;
#pragma unroll
  for (int s = 0; s < 8; ++s) {
    dy += offp[base + s * OFFSEG];
    dx += offp[base2 + s * OFFSEG];
  }
  float sy = (float)(ho - 1 + kk / 3) + dy;
  float sx = (float)(wo - 1 + kk % 3) + dx;
  float fy = floorf(sy), fx = floorf(sx);
  int y0 = (int)fy, x0 = (int)fx;
  float wy = sy - fy, wx = sx - fx;
  int y1 = y0 + 1, x1 = x0 + 1;
  int cy0 = min(max(y0, 0), Hx - 1), cy1 = min(max(y1, 0), Hx - 1);
  int cx0 = min(max(x0, 0), Wx - 1), cx1 = min(max(x1, 0), Wx - 1);
  bool vy0 = (y0 >= 0) & (y0 < Hx), vy1 = (y1 >= 0) & (y1 < Hx);
  bool vx0 = (x0 >= 0) & (x0 < Wx), vx1 = (x1 >= 0) & (x1 < Wx);
  short4 id;
  id.x = (short)(cy0 * Wx + cx0); id.y = (short)(cy0 * Wx + cx1);
  id.z = (short)(cy1 * Wx + cx0); id.w = (short)(cy1 * Wx + cx1);
  float4 wv;
  wv.x = (vy0 && vx0) ? (1.f - wy) * (1.f - wx) : 0.f;
  wv.y = (vy0 && vx1) ? (1.f - wy) * wx : 0.f;
  wv.z = (vy1 && vx0) ? wy * (1.f - wx) : 0.f;
  wv.w = (vy1 && vx1) ? wy * wx : 0.f;
  cidx[t] = id;
  cwt[t] = wv;
}

// ---------------- K4: sampler v8 — v6 + balanced position split ----------------
// Post-mortem v7 (62us, FAILED): coeff prefetch dbuf added VGPR+instr overhead
// without hiding latency (VGPR 68 not ~130 -> compiler sank the prefetch;
// occupancy fell). Reverted. v6's counters show the REAL residual: occupancy
// 30% vs the 50% that grid=1024 x 4 waves should give. Cause: kq work
// imbalance -- kq=0 blocks run 3 kks (48 iters), kq>=1 run 2 (32). Short
// blocks exit at t=2/3 and the tail runs 1 long block/CU. v8 rebalances:
// each block does ALL 9 kks over 1/4 of the positions (posq split) ->
// every block exactly 36 iters, zero tail. Staging identical to v6 (4x
// redundancy). Coeff loads stay coalesced (256-contiguous within 1024-
// window). One variable changed vs v6.
// blk = (posq<<8)|(g4<<3)|b, grid 1024, 32KB LDS. Pb layout unchanged.
__global__ __launch_bounds__(256) void sampler_kernel(
    const float* __restrict__ x, const short4* __restrict__ cidx,
    const float4* __restrict__ cwt, short* __restrict__ Pb) {
  __shared__ __align__(16) ushort4 ldsp[HW];   // 32768 B: [pixel]{4 bf16 cins}
  int blk = blockIdx.x;                     // 0..1023
  int b = blk & 7;
  int g4 = (blk >> 3) & 31;                 // cin-quad 0..31
  int posq = blk >> 8;                      // position quarter 0..3
  int cinq = g4 >> 3;                       // chunk quarter 0..3
  int e = g4 & 7;                           // quad slot within chunk (8 quads)
  int tid = threadIdx.x;

  // stage 4 planes -> bf16 interleaved. Coalesced f32 reads, 8B LDS writes.
  const float* p0 = x + (b * CIN + g4 * 4) * HW;
  const float* p1 = p0 + HW;
  const float* p2 = p0 + 2 * HW;
  const float* p3 = p0 + 3 * HW;
#pragma unroll
  for (int it = 0; it < 16; ++it) {
    int p = it * 256 + tid;
    ushort4 pk;
    pk.x = (unsigned short)f2bf(p0[p]);
    pk.y = (unsigned short)f2bf(p1[p]);
    pk.z = (unsigned short)f2bf(p2[p]);
    pk.w = (unsigned short)f2bf(p3[p]);
    ldsp[p] = pk;
  }
  __syncthreads();

  const int pbase = b * HW + posq * 1024 + tid;
  for (int kk = 0; kk < 9; ++kk) {
    int kcg = kk * 4 + cinq;                // 0..35
    const short4* cp = cidx + kk * M_ + pbase;
    const float4* wp = cwt + kk * M_ + pbase;
    short* pb = Pb + (kcg * M_ + pbase) * 32 + e * 4;
#pragma unroll
    for (int it = 0; it < 4; ++it) {
      short4 id = cp[it * 256];
      float4 wv = wp[it * 256];
      ushort4 A  = ldsp[(int)id.x];
      ushort4 Bv = ldsp[(int)id.y];
      ushort4 C  = ldsp[(int)id.z];
      ushort4 D  = ldsp[(int)id.w];
      float s0 = wv.x * b2f(A.x) + wv.y * b2f(Bv.x) + wv.z * b2f(C.x) + wv.w * b2f(D.x);
      float s1 = wv.x * b2f(A.y) + wv.y * b2f(Bv.y) + wv.z * b2f(C.y) + wv.w * b2f(D.y);
      float s2 = wv.x * b2f(A.z) + wv.y * b2f(Bv.z) + wv.z * b2f(C.z) + wv.w * b2f(D.z);
      float s3 = wv.x * b2f(A.w) + wv.y * b2f(Bv.w) + wv.z * b2f(C.w) + wv.w * b2f(D.w);
      union { short s[4]; int2 v; } bu;
      bu.s[0] = f2bf(s0);
      bu.s[1] = f2bf(s1);
      bu.s[2] = f2bf(s2);
      bu.s[3] = f2bf(s3);
      *(int2*)&pb[it * 256 * 32] = bu.v;
    }
  }
}

// ---------------- K5: single bf16 MFMA GEMM, m97-style async K-loop ----------------
// blk: mt = blk&255, ct = blk>>8 (ct-pair shares XCD -> Pb L2 reuse).
// Tile 128 cout x 128 m, K=1152 in 36 chunks of 32. Double-buffered 16KB LDS
// tiles staged by global_load_lds (flat 8KB A + 8KB B copies); ONE barrier per
// chunk; next chunk's DMA flies across the 16 MFMAs.
__global__ __launch_bounds__(256, 2) void gemm_kernel(
    const short* __restrict__ Wb, const short* __restrict__ Pb,
    float* __restrict__ y) {
  __shared__ __align__(16) short lds[2][8192];   // [buf][ A 4096 | B 4096 ] shorts

  int tid = threadIdx.x;
  int mt = blockIdx.x & 255;
  int ct = blockIdx.x >> 8;
  int cout0 = ct * 128;
  int m0 = mt * 128;

  int lane = tid & 63, wave = tid >> 6;
  int quad = lane >> 4, l16 = lane & 15;
  int wm = (wave & 1) << 6;          // cout sub-tile 0/64
  int wnm = (wave >> 1) << 6;        // m sub-tile 0/64

  // staging roles: waves 0,1 -> A halves; waves 2,3 -> B halves
  int isB = wave >> 1;
  int sub = wave & 1;
  const short* srcbase = isB ? (Pb + m0 * 32) : (Wb + cout0 * 32);
  const int sstride = isB ? (M_ * 32) : (256 * 32);
  const int soff = sub * 2048 + lane * 8;        // shorts
  const int doff = isB * 4096 + sub * 2048 + lane * 8;

  f32x4 zero = {0.f, 0.f, 0.f, 0.f};
  f32x4 acc[4][4];
#pragma unroll
  for (int i = 0; i < 4; ++i)
#pragma unroll
    for (int j = 0; j < 4; ++j) acc[i][j] = zero;

  // prologue: chunk 0 -> buf 0
  {
    const short* s = srcbase + soff;
    short* d = &lds[0][doff];
#pragma unroll
    for (int j = 0; j < 4; ++j)
      async_cp16(s + j * 512, d + j * 512);
  }

  for (int ch = 0; ch < NCH; ++ch) {
    int p = ch & 1;
    __syncthreads();                 // drains DMA -> buf p ready; frag reads of p^1 done
    if (ch < NCH - 1) {
      const short* s = srcbase + (ch + 1) * sstride + soff;
      short* d = &lds[p ^ 1][doff];
#pragma unroll
      for (int j = 0; j < 4; ++j)
        async_cp16(s + j * 512, d + j * 512);   // flies across the MFMAs below
    }
    const short* sa = &lds[p][0];
    const short* sb = &lds[p][4096];
    bf16x8 af[4], bfr[4];
#pragma unroll
    for (int i = 0; i < 4; ++i)
      af[i] = *(const bf16x8*)&sa[(wm + i * 16 + l16) * 32 + quad * 8];
#pragma unroll
    for (int j = 0; j < 4; ++j)
      bfr[j] = *(const bf16x8*)&sb[(wnm + j * 16 + l16) * 32 + quad * 8];
#pragma unroll
    for (int i = 0; i < 4; ++i)
#pragma unroll
      for (int j = 0; j < 4; ++j)
        acc[i][j] = __builtin_amdgcn_mfma_f32_16x16x32_bf16(af[i], bfr[j], acc[i][j], 0, 0, 0);
  }

  // epilogue: write y once (dconv bias cancels in BN mean-subtraction)
#pragma unroll
  for (int i = 0; i < 4; ++i) {
    int crow = cout0 + wm + i * 16 + quad * 4;
#pragma unroll
    for (int j = 0; j < 4; ++j) {
      int m = m0 + wnm + j * 16 + l16;
      int b = m >> 12;
      float* yp = y + (b * COUT + crow) * HW + (m & 4095);
#pragma unroll
      for (int r2 = 0; r2 < 4; ++r2)
        yp[r2 * HW] = acc[i][j][r2];
    }
  }
}

// ---------------- K6: BN batch stats (proven) ----------------
__global__ __launch_bounds__(256) void bn_stats_kernel(
    const float* __restrict__ y, float* __restrict__ mean, float* __restrict__ invstd) {
  int c = blockIdx.x;
  int tid = threadIdx.x;
  float s = 0.f, s2 = 0.f;
  for (int b = 0; b < B_; ++b) {
    const float4* p = (const float4*)(y + (b * COUT + c) * HW);
    for (int i = tid; i < HW / 4; i += 256) {
      float4 v = p[i];
      s += v.x + v.y + v.z + v.w;
      s2 = fmaf(v.x, v.x, s2); s2 = fmaf(v.y, v.y, s2);
      s2 = fmaf(v.z, v.z, s2); s2 = fmaf(v.w, v.w, s2);
    }
  }
#pragma unroll
  for (int o = 32; o > 0; o >>= 1) {
    s  += __shfl_down(s, o);
    s2 += __shfl_down(s2, o);
  }
  __shared__ float rs[4], rs2[4];
  int wid = tid >> 6, ln = tid & 63;
  if (ln == 0) { rs[wid] = s; rs2[wid] = s2; }
  __syncthreads();
  if (tid == 0) {
    float S  = rs[0] + rs[1] + rs[2] + rs[3];
    float S2 = rs2[0] + rs2[1] + rs2[2] + rs2[3];
    float m = S / 32768.f;
    float var = S2 / 32768.f - m * m;
    mean[c] = m;
    invstd[c] = rsqrtf(var + 1e-5f);
  }
}

// ---------------- K7: BN apply + SiLU, in place on y (= d_out) (proven) ----------------
__global__ __launch_bounds__(256) void bn_silu_kernel(
    float* __restrict__ y, const float* __restrict__ mean,
    const float* __restrict__ invstd, const float* __restrict__ gamma,
    const float* __restrict__ beta) {
  int i4 = blockIdx.x * 256 + threadIdx.x;   // 2097152 float4s
  int c = (i4 >> 10) & 255;
  float4 v = ((const float4*)y)[i4];
  float m = mean[c], sc = invstd[c] * gamma[c], bt = beta[c];
  float t0 = (v.x - m) * sc + bt;
  float t1 = (v.y - m) * sc + bt;
  float t2 = (v.z - m) * sc + bt;
  float t3 = (v.w - m) * sc + bt;
  float4 o;
  o.x = t0 / (1.f + expf(-t0));
  o.y = t1 / (1.f + expf(-t1));
  o.z = t2 / (1.f + expf(-t2));
  o.w = t3 / (1.f + expf(-t3));
  ((float4*)y)[i4] = o;
}

extern "C" void kernel_launch(void* const* d_in, const int* in_sizes, int n_in,
                              void* d_out, int out_size, void* d_ws, size_t ws_size,
                              hipStream_t stream) {
  const float* x     = (const float*)d_in[0];
  const float* ow    = (const float*)d_in[1];
  const float* ob    = (const float*)d_in[2];
  const float* dw    = (const float*)d_in[3];
  // d_in[4] = dconv bias: cancelled exactly by BN mean-subtraction
  const float* gamma = (const float*)d_in[5];
  const float* beta  = (const float*)d_in[6];
  float* y = (float*)d_out;                  // 8*256*4096 f32 — y buffer, finished in place

  // ws layout (float offsets), total 25,510,400 floats = 102.0 MB (ws = 256 MiB)
  float*  ws   = (float*)d_ws;
  short*  Pb   = (short*)ws;                 // 36*32768*32 shorts = 18874368 floats
  float*  offp = ws + 18874368;              // 8 * 589824 = 4718592
  short4* cidx = (short4*)(ws + 23592960);   // 9*32768 short4 = 589824 floats
  float4* cwt  = (float4*)(ws + 24182784);   // 9*32768 float4 = 1179648 floats
  short*  Wb   = (short*)(ws + 25362432);    // 294912 shorts = 147456 floats
  float*  mean   = ws + 25509888;            // 256
  float*  invstd = ws + 25510144;            // 256

  offset_conv_kernel<<<1024, 256, 0, stream>>>(x, ow, ob, offp);
  wt_cvt_kernel<<<1152, 256, 0, stream>>>(dw, Wb);
  coeff_kernel<<<1152, 256, 0, stream>>>(offp, cidx, cwt);
  sampler_kernel<<<1024, 256, 0, stream>>>(x, cidx, cwt, Pb);
  gemm_kernel<<<512, 256, 0, stream>>>(Wb, Pb, y);
  bn_stats_kernel<<<256, 256, 0, stream>>>(y, mean, invstd);
  bn_silu_kernel<<<8192, 256, 0, stream>>>(y, mean, invstd, gamma, beta);
}

// Round 9
// 194.004 us; speedup vs baseline: 1.1235x; 1.1006x over previous
//
#include <hip/hip_runtime.h>
#include <hip/hip_bf16.h>
#include <math.h>

// (B,Cin,H,W)=(8,128,64,64), Cout=256, K=3, stride=1, pad=1, dil=1
#define B_    8
#define CIN   128
#define Hx    64
#define Wx    64
#define COUT  256
#define HW    4096
#define KTOT  1152      // CIN*9
#define NOFF  18
#define M_    32768     // B*HW
#define OFFSEG (B_ * NOFF * HW)   // 589824 floats per cin-segment partial
#define NCH   36        // K-chunks (chunk = 32 k)

typedef short bf16x8 __attribute__((ext_vector_type(8)));
typedef float f32x4  __attribute__((ext_vector_type(4)));
typedef unsigned short us8 __attribute__((ext_vector_type(8)));

typedef __attribute__((address_space(1))) const unsigned int gu32;
typedef __attribute__((address_space(3))) unsigned int lu32;
static __device__ __forceinline__ void async_cp16(const short* g, short* l) {
  __builtin_amdgcn_global_load_lds((gu32*)g, (lu32*)l, 16, 0, 0);
}

static __device__ __forceinline__ short f2bf(float f) {
  __hip_bfloat16 h = __float2bfloat16(f);
  return *reinterpret_cast<short*>(&h);
}

static __device__ __forceinline__ float b2f(unsigned short u) {
  unsigned int v = ((unsigned int)u) << 16;
  return __uint_as_float(v);
}

// ---------------- K1: offset conv (round-8 proven) ----------------
__global__ __launch_bounds__(256, 4) void offset_conv_kernel(
    const float* __restrict__ x, const float* __restrict__ ow,
    const float* __restrict__ ob, float* __restrict__ offp) {
  __shared__ __align__(16) float lds_w[16 * 9 * 12];   // [ci][ch][12 (9 taps + pad)]
  int blk = blockIdx.x;                     // 0..1023
  int r = blk & 63, seg = (blk >> 6) & 7, chalf = blk >> 9;
  int tid = threadIdx.x;
  for (int i = tid; i < 16 * 9 * 12; i += 256) {
    int t = i % 12;
    int rem = i / 12;                       // ci*9 + ch
    int ch = rem % 9, ci = rem / 9;
    lds_w[i] = (t < 9) ? ow[(chalf * 9 + ch) * KTOT + (seg * 16 + ci) * 9 + t] : 0.f;
  }
  __syncthreads();

  int v = r * 256 + tid;                    // 0..16383
  int wp = v & 31, ho = (v >> 5) & 63, b = v >> 11;
  int wo0 = wp * 2;
  float acc0[9], acc1[9];
#pragma unroll
  for (int c = 0; c < 9; ++c) { acc0[c] = 0.f; acc1[c] = 0.f; }
  const float* xb = x + (b * CIN + seg * 16) * HW;
  for (int ci = 0; ci < 16; ++ci) {
    const float* xp = xb + ci * HW;
    float win[3][4];
#pragma unroll
    for (int ky = 0; ky < 3; ++ky) {
      int iy = ho - 1 + ky;
      bool rok = (iy >= 0) & (iy < Hx);
      const float* rowp = xp + iy * Wx;
#pragma unroll
      for (int c = 0; c < 4; ++c) {
        int ix = wo0 - 1 + c;
        win[ky][c] = (rok & (ix >= 0) & (ix < Wx)) ? rowp[ix] : 0.f;
      }
    }
    const float4* wq = (const float4*)&lds_w[ci * 108];
#pragma unroll
    for (int ch = 0; ch < 9; ++ch) {
      float4 w0 = wq[ch * 3 + 0];
      float4 w1 = wq[ch * 3 + 1];
      float4 w2 = wq[ch * 3 + 2];
      float a0 = acc0[ch], a1 = acc1[ch];
      a0 = fmaf(win[0][0], w0.x, a0); a1 = fmaf(win[0][1], w0.x, a1);
      a0 = fmaf(win[0][1], w0.y, a0); a1 = fmaf(win[0][2], w0.y, a1);
      a0 = fmaf(win[0][2], w0.z, a0); a1 = fmaf(win[0][3], w0.z, a1);
      a0 = fmaf(win[1][0], w0.w, a0); a1 = fmaf(win[1][1], w0.w, a1);
      a0 = fmaf(win[1][1], w1.x, a0); a1 = fmaf(win[1][2], w1.x, a1);
      a0 = fmaf(win[1][2], w1.y, a0); a1 = fmaf(win[1][3], w1.y, a1);
      a0 = fmaf(win[2][0], w1.z, a0); a1 = fmaf(win[2][1], w1.z, a1);
      a0 = fmaf(win[2][1], w1.w, a0); a1 = fmaf(win[2][2], w1.w, a1);
      a0 = fmaf(win[2][2], w2.x, a0); a1 = fmaf(win[2][3], w2.x, a1);
      acc0[ch] = a0; acc1[ch] = a1;
    }
  }
  float* op = offp + seg * OFFSEG + (b * NOFF + chalf * 9) * HW + ho * 64 + wo0;
#pragma unroll
  for (int c = 0; c < 9; ++c) {
    float bias = (seg == 0) ? ob[chalf * 9 + c] : 0.f;
    op[c * HW]     = acc0[c] + bias;
    op[c * HW + 1] = acc1[c] + bias;
  }
}

// ---------------- K2: weight -> bf16 blocked Wb[kc][cout][32] (proven) ----------------
__global__ __launch_bounds__(256) void wt_cvt_kernel(
    const float* __restrict__ w, short* __restrict__ Wb) {
  int t = blockIdx.x * 256 + threadIdx.x;   // 294912
  int ki = t & 31;
  int cout = (t >> 5) & 255;
  int kc = t >> 13;                         // 0..35
  int k = kc * 32 + ki;
  int kk = k >> 7, cin = k & 127;
  Wb[t] = f2bf(w[(cout * CIN + cin) * 9 + kk]);
}

// ---------------- K3: bilinear coefficient tables (proven, 8 partials) ----------------
__global__ __launch_bounds__(256) void coeff_kernel(
    const float* __restrict__ offp, short4* __restrict__ cidx, float4* __restrict__ cwt) {
  int t = blockIdx.x * 256 + threadIdx.x;   // 9*32768
  int m = t & (M_ - 1);
  int kk = t >> 15;                         // 0..8
  int b = m >> 12, ho = (m >> 6) & 63, wo = m & 63;
  int base = (b * NOFF + 2 * kk) * HW + (m & 4095);
  int base2 = base + HW;
  float dy = 0.f, dx = 0.f;
#pragma unroll
  for (int s = 0; s < 8; ++s) {
    dy += offp[base + s * OFFSEG];
    dx += offp[base2 + s * OFFSEG];
  }
  float sy = (float)(ho - 1 + kk / 3) + dy;
  float sx = (float)(wo - 1 + kk % 3) + dx;
  float fy = floorf(sy), fx = floorf(sx);
  int y0 = (int)fy, x0 = (int)fx;
  float wy = sy - fy, wx = sx - fx;
  int y1 = y0 + 1, x1 = x0 + 1;
  int cy0 = min(max(y0, 0), Hx - 1), cy1 = min(max(y1, 0), Hx - 1);
  int cx0 = min(max(x0, 0), Wx - 1), cx1 = min(max(x1, 0), Wx - 1);
  bool vy0 = (y0 >= 0) & (y0 < Hx), vy1 = (y1 >= 0) & (y1 < Hx);
  bool vx0 = (x0 >= 0) & (x0 < Wx), vx1 = (x1 >= 0) & (x1 < Wx);
  short4 id;
  id.x = (short)(cy0 * Wx + cx0); id.y = (short)(cy0 * Wx + cx1);
  id.z = (short)(cy1 * Wx + cx0); id.w = (short)(cy1 * Wx + cx1);
  float4 wv;
  wv.x = (vy0 && vx0) ? (1.f - wy) * (1.f - wx) : 0.f;
  wv.y = (vy0 && vx1) ? (1.f - wy) * wx : 0.f;
  wv.z = (vy1 && vx0) ? wy * (1.f - wx) : 0.f;
  wv.w = (vy1 && vx1) ? wy * wx : 0.f;
  cidx[t] = id;
  cwt[t] = wv;
}

// ---------------- K4: sampler v9 — 8-cin planes, ds_read_b128 gathers ----------------
// Post-mortem v8 (55.8us, imbalance theory falsified; occupancy unchanged):
// the ONLY lever that has moved this kernel is latency-event amortization
// per cin (v1->v6: events/cin halved -> time halved). Scheduling attempts
// (v2,v3,v4,v5,v7,v8) all <=0. v9 applies the lever again:
//  * 8 bf16 planes interleaved {c0..c7} per pixel = 16B/px = 64KB LDS.
//  * ONE ds_read_b128 per bilinear corner serves 8 cins (m134: b128 12cy
//    ~= 2x b64 throughput, HALF the latency events).
//  * coeff loads + stores amortize over 8 cins: 4.7M iters (v8: 9.4M);
//    stores become 16B int4 at Pb slot e8*8 (checked vs wt_cvt mapping:
//    ki = (g8&3)*8 + j).
//  * grid 512 = 2 blocks/CU (128KB LDS), 8 waves/CU; posq split kept
//    (v8 showed it cuts FETCH via L2 locality).
// blk = (posq<<7)|(g8<<3)|b, grid 512.
__global__ __launch_bounds__(256) void sampler_kernel(
    const float* __restrict__ x, const short4* __restrict__ cidx,
    const float4* __restrict__ cwt, short* __restrict__ Pb) {
  __shared__ __align__(16) us8 ldsp[HW];    // 65536 B: [pixel]{8 bf16 cins}
  int blk = blockIdx.x;                     // 0..511
  int b = blk & 7;
  int g8 = (blk >> 3) & 15;                 // cin-octet 0..15
  int posq = blk >> 7;                      // position quarter 0..3
  int cinq = g8 >> 2;                       // chunk quarter 0..3
  int e8 = g8 & 3;                          // octet slot within chunk (4 octets)
  int tid = threadIdx.x;

  // stage 8 planes -> bf16 interleaved. Coalesced f32 reads, 16B LDS writes.
  const float* p0 = x + (b * CIN + g8 * 8) * HW;
#pragma unroll
  for (int it = 0; it < 16; ++it) {
    int p = it * 256 + tid;
    us8 pk;
#pragma unroll
    for (int c = 0; c < 8; ++c)
      pk[c] = (unsigned short)f2bf(p0[c * HW + p]);
    ldsp[p] = pk;
  }
  __syncthreads();

  const int pbase = b * HW + posq * 1024 + tid;
  for (int kk = 0; kk < 9; ++kk) {
    int kcg = kk * 4 + cinq;                // 0..35
    const short4* cp = cidx + kk * M_ + pbase;
    const float4* wp = cwt + kk * M_ + pbase;
    short* pb = Pb + (kcg * M_ + pbase) * 32 + e8 * 8;
#pragma unroll
    for (int it = 0; it < 4; ++it) {
      short4 id = cp[it * 256];
      float4 wv = wp[it * 256];
      us8 A  = ldsp[(int)id.x];
      us8 Bv = ldsp[(int)id.y];
      us8 C  = ldsp[(int)id.z];
      us8 D  = ldsp[(int)id.w];
      union { short s[8]; int4 v; } bu;
#pragma unroll
      for (int c = 0; c < 8; ++c) {
        float s = wv.x * b2f(A[c]) + wv.y * b2f(Bv[c])
                + wv.z * b2f(C[c]) + wv.w * b2f(D[c]);
        bu.s[c] = f2bf(s);
      }
      *(int4*)&pb[it * 256 * 32] = bu.v;
    }
  }
}

// ---------------- K5: single bf16 MFMA GEMM, m97-style async K-loop ----------------
// blk: mt = blk&255, ct = blk>>8 (ct-pair shares XCD -> Pb L2 reuse).
// Tile 128 cout x 128 m, K=1152 in 36 chunks of 32. Double-buffered 16KB LDS
// tiles staged by global_load_lds (flat 8KB A + 8KB B copies); ONE barrier per
// chunk; next chunk's DMA flies across the 16 MFMAs.
__global__ __launch_bounds__(256, 2) void gemm_kernel(
    const short* __restrict__ Wb, const short* __restrict__ Pb,
    float* __restrict__ y) {
  __shared__ __align__(16) short lds[2][8192];   // [buf][ A 4096 | B 4096 ] shorts

  int tid = threadIdx.x;
  int mt = blockIdx.x & 255;
  int ct = blockIdx.x >> 8;
  int cout0 = ct * 128;
  int m0 = mt * 128;

  int lane = tid & 63, wave = tid >> 6;
  int quad = lane >> 4, l16 = lane & 15;
  int wm = (wave & 1) << 6;          // cout sub-tile 0/64
  int wnm = (wave >> 1) << 6;        // m sub-tile 0/64

  // staging roles: waves 0,1 -> A halves; waves 2,3 -> B halves
  int isB = wave >> 1;
  int sub = wave & 1;
  const short* srcbase = isB ? (Pb + m0 * 32) : (Wb + cout0 * 32);
  const int sstride = isB ? (M_ * 32) : (256 * 32);
  const int soff = sub * 2048 + lane * 8;        // shorts
  const int doff = isB * 4096 + sub * 2048 + lane * 8;

  f32x4 zero = {0.f, 0.f, 0.f, 0.f};
  f32x4 acc[4][4];
#pragma unroll
  for (int i = 0; i < 4; ++i)
#pragma unroll
    for (int j = 0; j < 4; ++j) acc[i][j] = zero;

  // prologue: chunk 0 -> buf 0
  {
    const short* s = srcbase + soff;
    short* d = &lds[0][doff];
#pragma unroll
    for (int j = 0; j < 4; ++j)
      async_cp16(s + j * 512, d + j * 512);
  }

  for (int ch = 0; ch < NCH; ++ch) {
    int p = ch & 1;
    __syncthreads();                 // drains DMA -> buf p ready; frag reads of p^1 done
    if (ch < NCH - 1) {
      const short* s = srcbase + (ch + 1) * sstride + soff;
      short* d = &lds[p ^ 1][doff];
#pragma unroll
      for (int j = 0; j < 4; ++j)
        async_cp16(s + j * 512, d + j * 512);   // flies across the MFMAs below
    }
    const short* sa = &lds[p][0];
    const short* sb = &lds[p][4096];
    bf16x8 af[4], bfr[4];
#pragma unroll
    for (int i = 0; i < 4; ++i)
      af[i] = *(const bf16x8*)&sa[(wm + i * 16 + l16) * 32 + quad * 8];
#pragma unroll
    for (int j = 0; j < 4; ++j)
      bfr[j] = *(const bf16x8*)&sb[(wnm + j * 16 + l16) * 32 + quad * 8];
#pragma unroll
    for (int i = 0; i < 4; ++i)
#pragma unroll
      for (int j = 0; j < 4; ++j)
        acc[i][j] = __builtin_amdgcn_mfma_f32_16x16x32_bf16(af[i], bfr[j], acc[i][j], 0, 0, 0);
  }

  // epilogue: write y once (dconv bias cancels in BN mean-subtraction)
#pragma unroll
  for (int i = 0; i < 4; ++i) {
    int crow = cout0 + wm + i * 16 + quad * 4;
#pragma unroll
    for (int j = 0; j < 4; ++j) {
      int m = m0 + wnm + j * 16 + l16;
      int b = m >> 12;
      float* yp = y + (b * COUT + crow) * HW + (m & 4095);
#pragma unroll
      for (int r2 = 0; r2 < 4; ++r2)
        yp[r2 * HW] = acc[i][j][r2];
    }
  }
}

// ---------------- K6: BN batch stats (proven) ----------------
__global__ __launch_bounds__(256) void bn_stats_kernel(
    const float* __restrict__ y, float* __restrict__ mean, float* __restrict__ invstd) {
  int c = blockIdx.x;
  int tid = threadIdx.x;
  float s = 0.f, s2 = 0.f;
  for (int b = 0; b < B_; ++b) {
    const float4* p = (const float4*)(y + (b * COUT + c) * HW);
    for (int i = tid; i < HW / 4; i += 256) {
      float4 v = p[i];
      s += v.x + v.y + v.z + v.w;
      s2 = fmaf(v.x, v.x, s2); s2 = fmaf(v.y, v.y, s2);
      s2 = fmaf(v.z, v.z, s2); s2 = fmaf(v.w, v.w, s2);
    }
  }
#pragma unroll
  for (int o = 32; o > 0; o >>= 1) {
    s  += __shfl_down(s, o);
    s2 += __shfl_down(s2, o);
  }
  __shared__ float rs[4], rs2[4];
  int wid = tid >> 6, ln = tid & 63;
  if (ln == 0) { rs[wid] = s; rs2[wid] = s2; }
  __syncthreads();
  if (tid == 0) {
    float S  = rs[0] + rs[1] + rs[2] + rs[3];
    float S2 = rs2[0] + rs2[1] + rs2[2] + rs2[3];
    float m = S / 32768.f;
    float var = S2 / 32768.f - m * m;
    mean[c] = m;
    invstd[c] = rsqrtf(var + 1e-5f);
  }
}

// ---------------- K7: BN apply + SiLU, in place on y (= d_out) (proven) ----------------
__global__ __launch_bounds__(256) void bn_silu_kernel(
    float* __restrict__ y, const float* __restrict__ mean,
    const float* __restrict__ invstd, const float* __restrict__ gamma,
    const float* __restrict__ beta) {
  int i4 = blockIdx.x * 256 + threadIdx.x;   // 2097152 float4s
  int c = (i4 >> 10) & 255;
  float4 v = ((const float4*)y)[i4];
  float m = mean[c], sc = invstd[c] * gamma[c], bt = beta[c];
  float t0 = (v.x - m) * sc + bt;
  float t1 = (v.y - m) * sc + bt;
  float t2 = (v.z - m) * sc + bt;
  float t3 = (v.w - m) * sc + bt;
  float4 o;
  o.x = t0 / (1.f + expf(-t0));
  o.y = t1 / (1.f + expf(-t1));
  o.z = t2 / (1.f + expf(-t2));
  o.w = t3 / (1.f + expf(-t3));
  ((float4*)y)[i4] = o;
}

extern "C" void kernel_launch(void* const* d_in, const int* in_sizes, int n_in,
                              void* d_out, int out_size, void* d_ws, size_t ws_size,
                              hipStream_t stream) {
  const float* x     = (const float*)d_in[0];
  const float* ow    = (const float*)d_in[1];
  const float* ob    = (const float*)d_in[2];
  const float* dw    = (const float*)d_in[3];
  // d_in[4] = dconv bias: cancelled exactly by BN mean-subtraction
  const float* gamma = (const float*)d_in[5];
  const float* beta  = (const float*)d_in[6];
  float* y = (float*)d_out;                  // 8*256*4096 f32 — y buffer, finished in place

  // ws layout (float offsets), total 25,510,400 floats = 102.0 MB (ws = 256 MiB)
  float*  ws   = (float*)d_ws;
  short*  Pb   = (short*)ws;                 // 36*32768*32 shorts = 18874368 floats
  float*  offp = ws + 18874368;              // 8 * 589824 = 4718592
  short4* cidx = (short4*)(ws + 23592960);   // 9*32768 short4 = 589824 floats
  float4* cwt  = (float4*)(ws + 24182784);   // 9*32768 float4 = 1179648 floats
  short*  Wb   = (short*)(ws + 25362432);    // 294912 shorts = 147456 floats
  float*  mean   = ws + 25509888;            // 256
  float*  invstd = ws + 25510144;            // 256

  offset_conv_kernel<<<1024, 256, 0, stream>>>(x, ow, ob, offp);
  wt_cvt_kernel<<<1152, 256, 0, stream>>>(dw, Wb);
  coeff_kernel<<<1152, 256, 0, stream>>>(offp, cidx, cwt);
  sampler_kernel<<<512, 256, 0, stream>>>(x, cidx, cwt, Pb);
  gemm_kernel<<<512, 256, 0, stream>>>(Wb, Pb, y);
  bn_stats_kernel<<<256, 256, 0, stream>>>(y, mean, invstd);
  bn_silu_kernel<<<8192, 256, 0, stream>>>(y, mean, invstd, gamma, beta);
}

// Round 10
// 182.572 us; speedup vs baseline: 1.1938x; 1.0626x over previous
//
#include <hip/hip_runtime.h>
#include <hip/hip_bf16.h>
#include <math.h>

// (B,Cin,H,W)=(8,128,64,64), Cout=256, K=3, stride=1, pad=1, dil=1
#define B_    8
#define CIN   128
#define Hx    64
#define Wx    64
#define COUT  256
#define HW    4096
#define KTOT  1152      // CIN*9
#define NOFF  18
#define M_    32768     // B*HW
#define OFFSEG (B_ * NOFF * HW)   // 589824 floats per cin-segment partial
#define NCH   36        // K-chunks (chunk = 32 k)

typedef short bf16x8 __attribute__((ext_vector_type(8)));
typedef float f32x4  __attribute__((ext_vector_type(4)));
typedef unsigned short us8 __attribute__((ext_vector_type(8)));

typedef __attribute__((address_space(1))) const unsigned int gu32;
typedef __attribute__((address_space(3))) unsigned int lu32;
static __device__ __forceinline__ void async_cp16(const short* g, short* l) {
  __builtin_amdgcn_global_load_lds((gu32*)g, (lu32*)l, 16, 0, 0);
}

static __device__ __forceinline__ short f2bf(float f) {
  __hip_bfloat16 h = __float2bfloat16(f);
  return *reinterpret_cast<short*>(&h);
}

static __device__ __forceinline__ float b2f(unsigned short u) {
  unsigned int v = ((unsigned int)u) << 16;
  return __uint_as_float(v);
}

// ---------------- K1': offset conv (proven) + wt_cvt merged (v10: -1 launch) ----------------
// blocks 0..1023: offset conv (unchanged round-8 body).
// blocks 1024..2175: weight -> bf16 blocked Wb[kc][cout][32] (unchanged body).
__global__ __launch_bounds__(256, 4) void pre_kernel(
    const float* __restrict__ x, const float* __restrict__ ow,
    const float* __restrict__ ob, float* __restrict__ offp,
    const float* __restrict__ dw, short* __restrict__ Wb) {
  __shared__ __align__(16) float lds_w[16 * 9 * 12];   // [ci][ch][12 (9 taps + pad)]
  int blk = blockIdx.x;
  int tid = threadIdx.x;
  if (blk >= 1024) {
    int t = (blk - 1024) * 256 + tid;       // 294912
    int ki = t & 31;
    int cout = (t >> 5) & 255;
    int kc = t >> 13;                       // 0..35
    int k = kc * 32 + ki;
    int kk = k >> 7, cin = k & 127;
    Wb[t] = f2bf(dw[(cout * CIN + cin) * 9 + kk]);
    return;
  }
  int r = blk & 63, seg = (blk >> 6) & 7, chalf = blk >> 9;
  for (int i = tid; i < 16 * 9 * 12; i += 256) {
    int t = i % 12;
    int rem = i / 12;                       // ci*9 + ch
    int ch = rem % 9, ci = rem / 9;
    lds_w[i] = (t < 9) ? ow[(chalf * 9 + ch) * KTOT + (seg * 16 + ci) * 9 + t] : 0.f;
  }
  __syncthreads();

  int v = r * 256 + tid;                    // 0..16383
  int wp = v & 31, ho = (v >> 5) & 63, b = v >> 11;
  int wo0 = wp * 2;
  float acc0[9], acc1[9];
#pragma unroll
  for (int c = 0; c < 9; ++c) { acc0[c] = 0.f; acc1[c] = 0.f; }
  const float* xb = x + (b * CIN + seg * 16) * HW;
  for (int ci = 0; ci < 16; ++ci) {
    const float* xp = xb + ci * HW;
    float win[3][4];
#pragma unroll
    for (int ky = 0; ky < 3; ++ky) {
      int iy = ho - 1 + ky;
      bool rok = (iy >= 0) & (iy < Hx);
      const float* rowp = xp + iy * Wx;
#pragma unroll
      for (int c = 0; c < 4; ++c) {
        int ix = wo0 - 1 + c;
        win[ky][c] = (rok & (ix >= 0) & (ix < Wx)) ? rowp[ix] : 0.f;
      }
    }
    const float4* wq = (const float4*)&lds_w[ci * 108];
#pragma unroll
    for (int ch = 0; ch < 9; ++ch) {
      float4 w0 = wq[ch * 3 + 0];
      float4 w1 = wq[ch * 3 + 1];
      float4 w2 = wq[ch * 3 + 2];
      float a0 = acc0[ch], a1 = acc1[ch];
      a0 = fmaf(win[0][0], w0.x, a0); a1 = fmaf(win[0][1], w0.x, a1);
      a0 = fmaf(win[0][1], w0.y, a0); a1 = fmaf(win[0][2], w0.y, a1);
      a0 = fmaf(win[0][2], w0.z, a0); a1 = fmaf(win[0][3], w0.z, a1);
      a0 = fmaf(win[1][0], w0.w, a0); a1 = fmaf(win[1][1], w0.w, a1);
      a0 = fmaf(win[1][1], w1.x, a0); a1 = fmaf(win[1][2], w1.x, a1);
      a0 = fmaf(win[1][2], w1.y, a0); a1 = fmaf(win[1][3], w1.y, a1);
      a0 = fmaf(win[2][0], w1.z, a0); a1 = fmaf(win[2][1], w1.z, a1);
      a0 = fmaf(win[2][1], w1.w, a0); a1 = fmaf(win[2][2], w1.w, a1);
      a0 = fmaf(win[2][2], w2.x, a0); a1 = fmaf(win[2][3], w2.x, a1);
      acc0[ch] = a0; acc1[ch] = a1;
    }
  }
  float* op = offp + seg * OFFSEG + (b * NOFF + chalf * 9) * HW + ho * 64 + wo0;
#pragma unroll
  for (int c = 0; c < 9; ++c) {
    float bias = (seg == 0) ? ob[chalf * 9 + c] : 0.f;
    op[c * HW]     = acc0[c] + bias;
    op[c * HW + 1] = acc1[c] + bias;
  }
}

// ---------------- K3: bilinear coefficient tables (proven, 8 partials) ----------------
__global__ __launch_bounds__(256) void coeff_kernel(
    const float* __restrict__ offp, short4* __restrict__ cidx, float4* __restrict__ cwt) {
  int t = blockIdx.x * 256 + threadIdx.x;   // 9*32768
  int m = t & (M_ - 1);
  int kk = t >> 15;                         // 0..8
  int b = m >> 12, ho = (m >> 6) & 63, wo = m & 63;
  int base = (b * NOFF + 2 * kk) * HW + (m & 4095);
  int base2 = base + HW;
  float dy = 0.f, dx = 0.f;
#pragma unroll
  for (int s = 0; s < 8; ++s) {
    dy += offp[base + s * OFFSEG];
    dx += offp[base2 + s * OFFSEG];
  }
  float sy = (float)(ho - 1 + kk / 3) + dy;
  float sx = (float)(wo - 1 + kk % 3) + dx;
  float fy = floorf(sy), fx = floorf(sx);
  int y0 = (int)fy, x0 = (int)fx;
  float wy = sy - fy, wx = sx - fx;
  int y1 = y0 + 1, x1 = x0 + 1;
  int cy0 = min(max(y0, 0), Hx - 1), cy1 = min(max(y1, 0), Hx - 1);
  int cx0 = min(max(x0, 0), Wx - 1), cx1 = min(max(x1, 0), Wx - 1);
  bool vy0 = (y0 >= 0) & (y0 < Hx), vy1 = (y1 >= 0) & (y1 < Hx);
  bool vx0 = (x0 >= 0) & (x0 < Wx), vx1 = (x1 >= 0) & (x1 < Wx);
  short4 id;
  id.x = (short)(cy0 * Wx + cx0); id.y = (short)(cy0 * Wx + cx1);
  id.z = (short)(cy1 * Wx + cx0); id.w = (short)(cy1 * Wx + cx1);
  float4 wv;
  wv.x = (vy0 && vx0) ? (1.f - wy) * (1.f - wx) : 0.f;
  wv.y = (vy0 && vx1) ? (1.f - wy) * wx : 0.f;
  wv.z = (vy1 && vx0) ? wy * (1.f - wx) : 0.f;
  wv.w = (vy1 && vx1) ? wy * wx : 0.f;
  cidx[t] = id;
  cwt[t] = wv;
}

// ---------------- K4: sampler v9 (proven, unchanged) — 8-cin planes, b128 gathers ----------------
// 8 bf16 planes interleaved {c0..c7} per pixel = 64KB LDS; one ds_read_b128
// per bilinear corner serves 8 cins; 16B int4 stores; posq split for L2
// locality. blk = (posq<<7)|(g8<<3)|b, grid 512, 2 blocks/CU.
__global__ __launch_bounds__(256) void sampler_kernel(
    const float* __restrict__ x, const short4* __restrict__ cidx,
    const float4* __restrict__ cwt, short* __restrict__ Pb) {
  __shared__ __align__(16) us8 ldsp[HW];    // 65536 B: [pixel]{8 bf16 cins}
  int blk = blockIdx.x;                     // 0..511
  int b = blk & 7;
  int g8 = (blk >> 3) & 15;                 // cin-octet 0..15
  int posq = blk >> 7;                      // position quarter 0..3
  int cinq = g8 >> 2;                       // chunk quarter 0..3
  int e8 = g8 & 3;                          // octet slot within chunk (4 octets)
  int tid = threadIdx.x;

  const float* p0 = x + (b * CIN + g8 * 8) * HW;
#pragma unroll
  for (int it = 0; it < 16; ++it) {
    int p = it * 256 + tid;
    us8 pk;
#pragma unroll
    for (int c = 0; c < 8; ++c)
      pk[c] = (unsigned short)f2bf(p0[c * HW + p]);
    ldsp[p] = pk;
  }
  __syncthreads();

  const int pbase = b * HW + posq * 1024 + tid;
  for (int kk = 0; kk < 9; ++kk) {
    int kcg = kk * 4 + cinq;                // 0..35
    const short4* cp = cidx + kk * M_ + pbase;
    const float4* wp = cwt + kk * M_ + pbase;
    short* pb = Pb + (kcg * M_ + pbase) * 32 + e8 * 8;
#pragma unroll
    for (int it = 0; it < 4; ++it) {
      short4 id = cp[it * 256];
      float4 wv = wp[it * 256];
      us8 A  = ldsp[(int)id.x];
      us8 Bv = ldsp[(int)id.y];
      us8 C  = ldsp[(int)id.z];
      us8 D  = ldsp[(int)id.w];
      union { short s[8]; int4 v; } bu;
#pragma unroll
      for (int c = 0; c < 8; ++c) {
        float s = wv.x * b2f(A[c]) + wv.y * b2f(Bv[c])
                + wv.z * b2f(C[c]) + wv.w * b2f(D[c]);
        bu.s[c] = f2bf(s);
      }
      *(int4*)&pb[it * 256 * 32] = bu.v;
    }
  }
}

// ---------------- K5': bf16 MFMA GEMM (proven K-loop) + BN partial stats ----------------
// v10: epilogue additionally reduces the block's 128x128 tile to per-channel
// (sum, sum^2) partials -> psum/psq[channel][mt] (exclusive ownership, no
// atomics, no zero-init needed). Replaces bn_stats' 33.5MB y re-read.
__global__ __launch_bounds__(256, 2) void gemm_kernel(
    const short* __restrict__ Wb, const short* __restrict__ Pb,
    float* __restrict__ y, float* __restrict__ psum, float* __restrict__ psq) {
  __shared__ __align__(16) short lds[2][8192];   // [buf][ A 4096 | B 4096 ] shorts

  int tid = threadIdx.x;
  int mt = blockIdx.x & 255;
  int ct = blockIdx.x >> 8;
  int cout0 = ct * 128;
  int m0 = mt * 128;

  int lane = tid & 63, wave = tid >> 6;
  int quad = lane >> 4, l16 = lane & 15;
  int wm = (wave & 1) << 6;          // cout sub-tile 0/64
  int wnm = (wave >> 1) << 6;        // m sub-tile 0/64

  // staging roles: waves 0,1 -> A halves; waves 2,3 -> B halves
  int isB = wave >> 1;
  int sub = wave & 1;
  const short* srcbase = isB ? (Pb + m0 * 32) : (Wb + cout0 * 32);
  const int sstride = isB ? (M_ * 32) : (256 * 32);
  const int soff = sub * 2048 + lane * 8;        // shorts
  const int doff = isB * 4096 + sub * 2048 + lane * 8;

  f32x4 zero = {0.f, 0.f, 0.f, 0.f};
  f32x4 acc[4][4];
#pragma unroll
  for (int i = 0; i < 4; ++i)
#pragma unroll
    for (int j = 0; j < 4; ++j) acc[i][j] = zero;

  // prologue: chunk 0 -> buf 0
  {
    const short* s = srcbase + soff;
    short* d = &lds[0][doff];
#pragma unroll
    for (int j = 0; j < 4; ++j)
      async_cp16(s + j * 512, d + j * 512);
  }

  for (int ch = 0; ch < NCH; ++ch) {
    int p = ch & 1;
    __syncthreads();                 // drains DMA -> buf p ready; frag reads of p^1 done
    if (ch < NCH - 1) {
      const short* s = srcbase + (ch + 1) * sstride + soff;
      short* d = &lds[p ^ 1][doff];
#pragma unroll
      for (int j = 0; j < 4; ++j)
        async_cp16(s + j * 512, d + j * 512);   // flies across the MFMAs below
    }
    const short* sa = &lds[p][0];
    const short* sb = &lds[p][4096];
    bf16x8 af[4], bfr[4];
#pragma unroll
    for (int i = 0; i < 4; ++i)
      af[i] = *(const bf16x8*)&sa[(wm + i * 16 + l16) * 32 + quad * 8];
#pragma unroll
    for (int j = 0; j < 4; ++j)
      bfr[j] = *(const bf16x8*)&sb[(wnm + j * 16 + l16) * 32 + quad * 8];
#pragma unroll
    for (int i = 0; i < 4; ++i)
#pragma unroll
      for (int j = 0; j < 4; ++j)
        acc[i][j] = __builtin_amdgcn_mfma_f32_16x16x32_bf16(af[i], bfr[j], acc[i][j], 0, 0, 0);
  }

  // epilogue 1: write y once (dconv bias cancels in BN mean-subtraction)
#pragma unroll
  for (int i = 0; i < 4; ++i) {
    int crow = cout0 + wm + i * 16 + quad * 4;
#pragma unroll
    for (int j = 0; j < 4; ++j) {
      int m = m0 + wnm + j * 16 + l16;
      int b = m >> 12;
      float* yp = y + (b * COUT + crow) * HW + (m & 4095);
#pragma unroll
      for (int r2 = 0; r2 < 4; ++r2)
        yp[r2 * HW] = acc[i][j][r2];
    }
  }

  // epilogue 2: per-channel (sum, sum^2) partials over this block's 128 m.
  // channel cl = wm + i*16 + quad*4 + r2; its 128 m live in 2 waves (wnm
  // halves) x 16 l16 lanes x 4 j. Reduce j in-reg, l16 via shfl (stays
  // within the quad's contiguous 16 lanes), halves via LDS.
  __syncthreads();                   // all lds frag reads done; reuse as scratch
  float* redsum = (float*)&lds[0][0];          // [2][128]
  float* redsq  = redsum + 256;
#pragma unroll
  for (int i = 0; i < 4; ++i) {
#pragma unroll
    for (int r2 = 0; r2 < 4; ++r2) {
      float s = 0.f, q = 0.f;
#pragma unroll
      for (int j = 0; j < 4; ++j) {
        float v = acc[i][j][r2];
        s += v;
        q = fmaf(v, v, q);
      }
#pragma unroll
      for (int o = 8; o > 0; o >>= 1) {
        s += __shfl_down(s, o);
        q += __shfl_down(q, o);
      }
      if (l16 == 0) {
        int cl = wm + i * 16 + quad * 4 + r2;    // 0..127
        int half = wave >> 1;
        redsum[half * 128 + cl] = s;
        redsq [half * 128 + cl] = q;
      }
    }
  }
  __syncthreads();
  if (tid < 128) {
    float s = redsum[tid] + redsum[128 + tid];
    float q = redsq [tid] + redsq [128 + tid];
    psum[(cout0 + tid) * 256 + mt] = s;
    psq [(cout0 + tid) * 256 + mt] = q;
  }
}

// ---------------- K6': BN finalize from 0.5MB partials (replaces bn_stats) ----------------
__global__ __launch_bounds__(256) void bn_finalize_kernel(
    const float* __restrict__ psum, const float* __restrict__ psq,
    float* __restrict__ mean, float* __restrict__ invstd) {
  int c = blockIdx.x;
  int tid = threadIdx.x;
  float s = psum[c * 256 + tid];
  float q = psq[c * 256 + tid];
#pragma unroll
  for (int o = 32; o > 0; o >>= 1) {
    s += __shfl_down(s, o);
    q += __shfl_down(q, o);
  }
  __shared__ float rs[4], rq[4];
  int wid = tid >> 6, ln = tid & 63;
  if (ln == 0) { rs[wid] = s; rq[wid] = q; }
  __syncthreads();
  if (tid == 0) {
    float S = rs[0] + rs[1] + rs[2] + rs[3];
    float Q = rq[0] + rq[1] + rq[2] + rq[3];
    float m = S / 32768.f;
    mean[c] = m;
    invstd[c] = rsqrtf(Q / 32768.f - m * m + 1e-5f);
  }
}

// ---------------- K7: BN apply + SiLU, in place on y (= d_out) (proven) ----------------
__global__ __launch_bounds__(256) void bn_silu_kernel(
    float* __restrict__ y, const float* __restrict__ mean,
    const float* __restrict__ invstd, const float* __restrict__ gamma,
    const float* __restrict__ beta) {
  int i4 = blockIdx.x * 256 + threadIdx.x;   // 2097152 float4s
  int c = (i4 >> 10) & 255;
  float4 v = ((const float4*)y)[i4];
  float m = mean[c], sc = invstd[c] * gamma[c], bt = beta[c];
  float t0 = (v.x - m) * sc + bt;
  float t1 = (v.y - m) * sc + bt;
  float t2 = (v.z - m) * sc + bt;
  float t3 = (v.w - m) * sc + bt;
  float4 o;
  o.x = t0 / (1.f + expf(-t0));
  o.y = t1 / (1.f + expf(-t1));
  o.z = t2 / (1.f + expf(-t2));
  o.w = t3 / (1.f + expf(-t3));
  ((float4*)y)[i4] = o;
}

extern "C" void kernel_launch(void* const* d_in, const int* in_sizes, int n_in,
                              void* d_out, int out_size, void* d_ws, size_t ws_size,
                              hipStream_t stream) {
  const float* x     = (const float*)d_in[0];
  const float* ow    = (const float*)d_in[1];
  const float* ob    = (const float*)d_in[2];
  const float* dw    = (const float*)d_in[3];
  // d_in[4] = dconv bias: cancelled exactly by BN mean-subtraction
  const float* gamma = (const float*)d_in[5];
  const float* beta  = (const float*)d_in[6];
  float* y = (float*)d_out;                  // 8*256*4096 f32 — y buffer, finished in place

  // ws layout (float offsets), total 25,641,472 floats = 102.5 MB (ws = 256 MiB)
  float*  ws   = (float*)d_ws;
  short*  Pb   = (short*)ws;                 // 36*32768*32 shorts = 18874368 floats
  float*  offp = ws + 18874368;              // 8 * 589824 = 4718592
  short4* cidx = (short4*)(ws + 23592960);   // 9*32768 short4 = 589824 floats
  float4* cwt  = (float4*)(ws + 24182784);   // 9*32768 float4 = 1179648 floats
  short*  Wb   = (short*)(ws + 25362432);    // 294912 shorts = 147456 floats
  float*  mean   = ws + 25509888;            // 256
  float*  invstd = ws + 25510144;            // 256
  float*  psum   = ws + 25510400;            // 256*256 = 65536
  float*  psq    = ws + 25575936;            // 65536

  pre_kernel<<<2176, 256, 0, stream>>>(x, ow, ob, offp, dw, Wb);
  coeff_kernel<<<1152, 256, 0, stream>>>(offp, cidx, cwt);
  sampler_kernel<<<512, 256, 0, stream>>>(x, cidx, cwt, Pb);
  gemm_kernel<<<512, 256, 0, stream>>>(Wb, Pb, y, psum, psq);
  bn_finalize_kernel<<<256, 256, 0, stream>>>(psum, psq, mean, invstd);
  bn_silu_kernel<<<8192, 256, 0, stream>>>(y, mean, invstd, gamma, beta);
}